// Round 5
// baseline (577.582 us; speedup 1.0000x reference)
//
#include <hip/hip_runtime.h>
#include <math.h>

#define KC 16
#define DF 256
#define ANB 64            // nodes per assign block

// ws layout
#define WS_POOLED 0          // [16*256] S^T F accumulator (floats)
#define WS_CS     4096       // [16] cluster sizes
#define WS_M      4112       // [16] m_k = sum_e val*S[row][k]
#define WS_TR     4128       // trace accumulator
#define WS_ESUM   4129       // sum of edge_val (= 2*n_edges)
#define WS_TOTAL  4130
#define SHDW_OFF_BYTES 16640 // fp8 S shadow, 16 B/node, 16B-aligned

// NOTE: no __has_builtin / arch preprocessor gating (host/device pass divergence
// caused the round-0 core dump). gfx950 always has the fp8 cvt builtins.

typedef float floatx2 __attribute__((ext_vector_type(2)));

__global__ void zero_ws_kernel(float* __restrict__ ws) {
  int i = blockIdx.x * blockDim.x + threadIdx.x;
  if (i < WS_TOTAL) ws[i] = 0.0f;
}

// 16 fp8 (OCP e4m3fn) -> 16 f32 via 8 packed HW converts.
__device__ __forceinline__ void cvt16_fp8(uint4 u, float* f) {
  floatx2 p;
  p = __builtin_amdgcn_cvt_pk_f32_fp8(u.x, false); f[0] = p[0];  f[1] = p[1];
  p = __builtin_amdgcn_cvt_pk_f32_fp8(u.x, true);  f[2] = p[0];  f[3] = p[1];
  p = __builtin_amdgcn_cvt_pk_f32_fp8(u.y, false); f[4] = p[0];  f[5] = p[1];
  p = __builtin_amdgcn_cvt_pk_f32_fp8(u.y, true);  f[6] = p[0];  f[7] = p[1];
  p = __builtin_amdgcn_cvt_pk_f32_fp8(u.z, false); f[8] = p[0];  f[9] = p[1];
  p = __builtin_amdgcn_cvt_pk_f32_fp8(u.z, true);  f[10] = p[0]; f[11] = p[1];
  p = __builtin_amdgcn_cvt_pk_f32_fp8(u.w, false); f[12] = p[0]; f[13] = p[1];
  p = __builtin_amdgcn_cvt_pk_f32_fp8(u.w, true);  f[14] = p[0]; f[15] = p[1];
}

__device__ __forceinline__ void acc_edge1(uint4 A, uint4 B, float vq,
                                          float* m, float& tr, float& es) {
  float a[16], bb[16];
  cvt16_fp8(A, a); cvt16_fp8(B, bb);
  float d = 0.f;
  #pragma unroll
  for (int k = 0; k < 16; ++k) d += a[k] * bb[k];
  tr += vq * d; es += vq;
  #pragma unroll
  for (int k = 0; k < 16; ++k) m[k] += vq * a[k];
}

// ---------------------------------------------------------------------------
// FUSED assign+pool. r4 diagnosis: assign had grid=391 blocks on 256 CUs
// (Occ 15%, VALUBusy 11%) -> latency-bound, and pool re-read all of F.
// Now: 64 nodes/block (grid ~1563), 4 waves K-split the 256 features
// (wave p covers features c*64 + [p*16, p*16+16) of each 64-feature chunk),
// partials combined in LDS, wave 0 does softmax, then the SAME block
// computes the pooled partial S^T F by re-staging its F tile (L2-hot)
// -> pool_kernel eliminated (one full 102 MB F pass removed).
// LDS: 2*64*65*4 + 64*20*4 = 38400 B -> 4 blocks/CU, 16 waves/CU.
// ---------------------------------------------------------------------------
__global__ void __launch_bounds__(256, 4) assign_fused_kernel(
    const float* __restrict__ F, const float* __restrict__ W,
    const float* __restrict__ b, float* __restrict__ S,
    unsigned* __restrict__ Sh, float* __restrict__ ws, int n) {
  __shared__ float Ft[2][64 * 65];   // chunk staging, transposed: [d_local*65 + node]
  __shared__ float Sl[64 * 20];      // S for the block's 64 nodes, stride 20 (16B-aligned)
  const int t = threadIdx.x;
  const int p  = t >> 6;             // wave id 0..3 (feature split)
  const int pu = __builtin_amdgcn_readfirstlane(p);  // explicitly wave-uniform
  const int nl = t & 63;             // node within block
  const int base = blockIdx.x << 6;
  const bool interior = (base + ANB <= n);

  float4 pref[4];
  auto load_chunk = [&](int c) {
    #pragma unroll
    for (int r = 0; r < 4; ++r) {
      const int li = (r << 8) + t;   // 0..1023
      const int nd = li >> 4;        // node 0..63
      const int f4 = li & 15;        // float4 slot within 64-feature chunk
      if (interior || base + nd < n)
        pref[r] = *(const float4*)&F[(size_t)(base + nd) * DF + (c << 6) + (f4 << 2)];
      else
        pref[r] = make_float4(0.f, 0.f, 0.f, 0.f);
    }
  };
  auto store_chunk = [&](int buf) {
    float* __restrict__ Fb = Ft[buf];
    #pragma unroll
    for (int r = 0; r < 4; ++r) {
      const int li = (r << 8) + t;
      const int nd = li >> 4;
      const int d0 = (li & 15) << 2;
      Fb[(d0 + 0) * 65 + nd] = pref[r].x;
      Fb[(d0 + 1) * 65 + nd] = pref[r].y;
      Fb[(d0 + 2) * 65 + nd] = pref[r].z;
      Fb[(d0 + 3) * 65 + nd] = pref[r].w;
    }
  };

  // ---- phase 1: partial logits (wave p covers 16 features per chunk) ----
  float acc[KC];
  #pragma unroll
  for (int k = 0; k < KC; ++k) acc[k] = 0.f;

  load_chunk(0);
  #pragma unroll
  for (int c = 0; c < 4; ++c) {
    store_chunk(c & 1);
    __syncthreads();
    if (c < 3) load_chunk(c + 1);   // next chunk in flight during compute
    const float* __restrict__ Fb = Ft[c & 1];
    #pragma unroll
    for (int j = 0; j < 16; ++j) {
      const float fv = Fb[((pu << 4) + j) * 65 + nl];
      const float* __restrict__ Wg = &W[(size_t)((c << 6) + (pu << 4) + j) * KC];
      #pragma unroll
      for (int k = 0; k < KC; ++k) acc[k] += fv * Wg[k];
    }
    __syncthreads();
  }

  // ---- phase 2: combine the 4 wave-partials via LDS (reuse Ft[0]) ----
  float* __restrict__ red = &Ft[0][0];       // 4096 floats used of 4160
  #pragma unroll
  for (int k4 = 0; k4 < 4; ++k4)
    *(float4*)&red[(size_t)((p << 6) + nl) * KC + (k4 << 2)] =
        make_float4(acc[k4 * 4 + 0], acc[k4 * 4 + 1],
                    acc[k4 * 4 + 2], acc[k4 * 4 + 3]);
  __syncthreads();

  // ---- phase 3: softmax + S/Sh/Sl writes + cluster sizes (wave 0) ----
  if (t < 64) {
    float l[KC];
    #pragma unroll
    for (int k = 0; k < KC; ++k)
      l[k] = red[t * KC + k] + red[(64 + t) * KC + k]
           + red[(128 + t) * KC + k] + red[(192 + t) * KC + k] + b[k];
    float mx = -1e30f;
    #pragma unroll
    for (int k = 0; k < KC; ++k) mx = fmaxf(mx, l[k]);
    float sum = 0.f;
    #pragma unroll
    for (int k = 0; k < KC; ++k) { l[k] = __expf(l[k] - mx); sum += l[k]; }
    const float inv = 1.0f / sum;
    #pragma unroll
    for (int k = 0; k < KC; ++k) l[k] *= inv;
    const bool valid = base + t < n;
    if (!valid) {
      #pragma unroll
      for (int k = 0; k < KC; ++k) l[k] = 0.f;
    }
    if (valid) {
      const int node = base + t;
      float4* __restrict__ So = (float4*)&S[(size_t)node * KC];
      So[0] = make_float4(l[0],  l[1],  l[2],  l[3]);
      So[1] = make_float4(l[4],  l[5],  l[6],  l[7]);
      So[2] = make_float4(l[8],  l[9],  l[10], l[11]);
      So[3] = make_float4(l[12], l[13], l[14], l[15]);
      if (Sh) {
        unsigned w0, w1, w2, w3;
        w0 = __builtin_amdgcn_cvt_pk_fp8_f32(l[0],  l[1],  0,  false);
        w0 = __builtin_amdgcn_cvt_pk_fp8_f32(l[2],  l[3],  w0, true);
        w1 = __builtin_amdgcn_cvt_pk_fp8_f32(l[4],  l[5],  0,  false);
        w1 = __builtin_amdgcn_cvt_pk_fp8_f32(l[6],  l[7],  w1, true);
        w2 = __builtin_amdgcn_cvt_pk_fp8_f32(l[8],  l[9],  0,  false);
        w2 = __builtin_amdgcn_cvt_pk_fp8_f32(l[10], l[11], w2, true);
        w3 = __builtin_amdgcn_cvt_pk_fp8_f32(l[12], l[13], 0,  false);
        w3 = __builtin_amdgcn_cvt_pk_fp8_f32(l[14], l[15], w3, true);
        *(uint4*)&Sh[(size_t)node * 4] = make_uint4(w0, w1, w2, w3);
      }
    }
    #pragma unroll
    for (int k = 0; k < KC; ++k) Sl[t * 20 + k] = l[k];
    // cluster sizes: butterfly over the full wave (t<64 == wave 0)
    #pragma unroll
    for (int off = 1; off < 64; off <<= 1) {
      #pragma unroll
      for (int k = 0; k < KC; ++k) l[k] += __shfl_xor(l[k], off);
    }
    if (t == 0) {
      #pragma unroll
      for (int k = 0; k < KC; ++k) atomicAdd(&ws[WS_CS + k], l[k]);
    }
  }
  __syncthreads();

  // ---- phase 4: pooled partial S^T F, re-staging chunks (L2-hot) ----
  // thread (p,nl): feature column d = c*64 + nl, clusters k = 4p..4p+3
  float accp[16];
  #pragma unroll
  for (int i = 0; i < 16; ++i) accp[i] = 0.f;

  load_chunk(0);
  #pragma unroll
  for (int c = 0; c < 4; ++c) {
    store_chunk(c & 1);
    __syncthreads();
    if (c < 3) load_chunk(c + 1);
    const float* __restrict__ Fb = Ft[c & 1];
    const int kb = p << 2;
    #pragma unroll 8
    for (int node = 0; node < 64; ++node) {
      const float fv = Fb[nl * 65 + node];
      const float4 sv = *(const float4*)&Sl[node * 20 + kb];  // wave-broadcast
      accp[c * 4 + 0] += fv * sv.x;
      accp[c * 4 + 1] += fv * sv.y;
      accp[c * 4 + 2] += fv * sv.z;
      accp[c * 4 + 3] += fv * sv.w;
    }
    __syncthreads();
  }
  #pragma unroll
  for (int c = 0; c < 4; ++c) {
    const int d = (c << 6) + nl;
    #pragma unroll
    for (int e = 0; e < 4; ++e)
      atomicAdd(&ws[WS_POOLED + (size_t)((p << 2) + e) * DF + d], accp[c * 4 + e]);
  }
}

// ---------------------------------------------------------------------------
// Edge pass (fp8 S): contiguous 2048-edge chunk per block, all 16 S-gathers
// issued into named registers before compute (r4: dropped below top-5).
// ---------------------------------------------------------------------------
__global__ void __launch_bounds__(256) edge_kernel_fp8(
    const int* __restrict__ erow, const int* __restrict__ ecol,
    const float* __restrict__ evl, const uint4* __restrict__ S8,
    float* __restrict__ ws, int ne) {
  __shared__ float red[KC + 2];
  const int t = threadIdx.x;
  if (t < KC + 2) red[t] = 0.0f;
  __syncthreads();

  float m[KC];
  #pragma unroll
  for (int i = 0; i < KC; ++i) m[i] = 0.f;
  float tr = 0.f, es = 0.f;

  const int cbase = blockIdx.x << 11;     // 2048 edges per block
  const int base = cbase + t;
  int r[8], c[8];
  float v[8];
  if (cbase + 2048 <= ne) {               // interior fast path
    #pragma unroll
    for (int i = 0; i < 8; ++i) {
      const int e = base + (i << 8);
      r[i] = erow[e]; c[i] = ecol[e]; v[i] = evl[e];
    }
  } else {
    #pragma unroll
    for (int i = 0; i < 8; ++i) {
      const int e = base + (i << 8);
      const bool ok = e < ne;
      r[i] = ok ? erow[e] : 0;
      c[i] = ok ? ecol[e] : 0;
      v[i] = ok ? evl[e] : 0.f;
    }
  }

  const uint4 A0 = S8[r[0]], B0 = S8[c[0]], A1 = S8[r[1]], B1 = S8[c[1]],
              A2 = S8[r[2]], B2 = S8[c[2]], A3 = S8[r[3]], B3 = S8[c[3]],
              A4 = S8[r[4]], B4 = S8[c[4]], A5 = S8[r[5]], B5 = S8[c[5]],
              A6 = S8[r[6]], B6 = S8[c[6]], A7 = S8[r[7]], B7 = S8[c[7]];
  acc_edge1(A0, B0, v[0], m, tr, es);
  acc_edge1(A1, B1, v[1], m, tr, es);
  acc_edge1(A2, B2, v[2], m, tr, es);
  acc_edge1(A3, B3, v[3], m, tr, es);
  acc_edge1(A4, B4, v[4], m, tr, es);
  acc_edge1(A5, B5, v[5], m, tr, es);
  acc_edge1(A6, B6, v[6], m, tr, es);
  acc_edge1(A7, B7, v[7], m, tr, es);

  #pragma unroll
  for (int off = 1; off < 64; off <<= 1) {
    tr += __shfl_xor(tr, off);
    es += __shfl_xor(es, off);
    #pragma unroll
    for (int i = 0; i < KC; ++i) m[i] += __shfl_xor(m[i], off);
  }
  if ((t & 63) == 0) {
    atomicAdd(&red[KC], tr);
    atomicAdd(&red[KC + 1], es);
    #pragma unroll
    for (int i = 0; i < KC; ++i) atomicAdd(&red[i], m[i]);
  }
  __syncthreads();
  if (t < KC)            atomicAdd(&ws[WS_M + t], red[t]);
  else if (t == KC)      atomicAdd(&ws[WS_TR], red[KC]);
  else if (t == KC + 1)  atomicAdd(&ws[WS_ESUM], red[KC + 1]);
}

// fp32 fallback (ws too small for the fp8 shadow) — runtime choice.
__global__ void __launch_bounds__(256) edge_kernel_f32(
    const int* __restrict__ erow, const int* __restrict__ ecol,
    const float* __restrict__ evl, const float* __restrict__ S,
    float* __restrict__ ws, int ne) {
  __shared__ float red[KC + 2];
  const int t = threadIdx.x;
  if (t < KC + 2) red[t] = 0.0f;
  __syncthreads();
  float m[KC];
  #pragma unroll
  for (int i = 0; i < KC; ++i) m[i] = 0.f;
  float tr = 0.f, es = 0.f;
  const int stride = gridDim.x * blockDim.x;
  for (int e = blockIdx.x * blockDim.x + t; e < ne; e += stride) {
    const int r = erow[e];
    const int c = ecol[e];
    const float v = evl[e];
    const float4* __restrict__ Sr = (const float4*)(S + (size_t)r * KC);
    const float4* __restrict__ Sc = (const float4*)(S + (size_t)c * KC);
    const float4 a0 = Sr[0], a1 = Sr[1], a2 = Sr[2], a3 = Sr[3];
    const float4 b0 = Sc[0], b1 = Sc[1], b2 = Sc[2], b3 = Sc[3];
    float d = a0.x*b0.x + a0.y*b0.y + a0.z*b0.z + a0.w*b0.w
            + a1.x*b1.x + a1.y*b1.y + a1.z*b1.z + a1.w*b1.w
            + a2.x*b2.x + a2.y*b2.y + a2.z*b2.z + a2.w*b2.w
            + a3.x*b3.x + a3.y*b3.y + a3.z*b3.z + a3.w*b3.w;
    tr += v * d; es += v;
    m[0]+=v*a0.x; m[1]+=v*a0.y; m[2]+=v*a0.z; m[3]+=v*a0.w;
    m[4]+=v*a1.x; m[5]+=v*a1.y; m[6]+=v*a1.z; m[7]+=v*a1.w;
    m[8]+=v*a2.x; m[9]+=v*a2.y; m[10]+=v*a2.z; m[11]+=v*a2.w;
    m[12]+=v*a3.x; m[13]+=v*a3.y; m[14]+=v*a3.z; m[15]+=v*a3.w;
  }
  #pragma unroll
  for (int off = 1; off < 64; off <<= 1) {
    tr += __shfl_xor(tr, off);
    es += __shfl_xor(es, off);
    #pragma unroll
    for (int i = 0; i < KC; ++i) m[i] += __shfl_xor(m[i], off);
  }
  if ((t & 63) == 0) {
    atomicAdd(&red[KC], tr);
    atomicAdd(&red[KC + 1], es);
    #pragma unroll
    for (int i = 0; i < KC; ++i) atomicAdd(&red[i], m[i]);
  }
  __syncthreads();
  if (t < KC)            atomicAdd(&ws[WS_M + t], red[t]);
  else if (t == KC)      atomicAdd(&ws[WS_TR], red[KC]);
  else if (t == KC + 1)  atomicAdd(&ws[WS_ESUM], red[KC + 1]);
}

__global__ void finalize_kernel(const float* __restrict__ ws,
                                float* __restrict__ out, int n) {
  const int idx = blockIdx.x * 256 + threadIdx.x;
  const float alpha = 1.6732632423543772f;
  const float scale = 1.0507009873554805f;
  if (idx < KC * DF) {
    const int k = idx >> 8;
    const float x = ws[WS_POOLED + idx] / ws[WS_CS + k];
    const float r = x > 0.f ? x : alpha * expm1f(x);
    out[idx] = scale * r;
  }
  if (idx == 0) {
    const float esum = ws[WS_ESUM];   // = 2 * n_edges
    const float tr = ws[WS_TR];
    float sm2 = 0.f, sc2 = 0.f;
    for (int i = 0; i < KC; ++i) {
      const float mi = ws[WS_M + i];
      sm2 += mi * mi;
      const float ci = ws[WS_CS + i];
      sc2 += ci * ci;
    }
    const float spectral = -(tr - sm2 / esum) / esum;
    const float collapse = 0.1f * (sqrtf(sc2) / (float)n * 4.0f - 1.0f);
    const size_t off = (size_t)(KC * DF) + (size_t)n * KC;
    out[off] = spectral;
    out[off + 1] = collapse;
  }
}

extern "C" void kernel_launch(void* const* d_in, const int* in_sizes, int n_in,
                              void* d_out, int out_size, void* d_ws, size_t ws_size,
                              hipStream_t stream) {
  const float* F   = (const float*)d_in[0];
  const float* W   = (const float*)d_in[1];
  const float* b   = (const float*)d_in[2];
  const int* erow  = (const int*)d_in[3];
  const int* ecol  = (const int*)d_in[4];
  const float* evl = (const float*)d_in[5];
  const int n  = in_sizes[0] / DF;
  const int ne = in_sizes[3];
  float* out = (float*)d_out;
  float* S   = out + KC * DF;      // assignments live directly in d_out
  float* ws  = (float*)d_ws;

  const size_t shadow_bytes = (size_t)n * 16;   // fp8: 16 B/node
  const bool use_shadow = ws_size >= (size_t)SHDW_OFF_BYTES + shadow_bytes + 64;
  unsigned* Sh = use_shadow ? (unsigned*)((char*)d_ws + SHDW_OFF_BYTES) : nullptr;

  zero_ws_kernel<<<(WS_TOTAL + 255) / 256, 256, 0, stream>>>(ws);
  const int ag = (n + ANB - 1) >> 6;
  assign_fused_kernel<<<ag, 256, 0, stream>>>(F, W, b, S, Sh, ws, n);
  if (use_shadow) {
    const int eg = (ne + 2047) >> 11;           // one 2048-edge chunk per block
    edge_kernel_fp8<<<eg, 256, 0, stream>>>(erow, ecol, evl, (const uint4*)Sh, ws, ne);
  } else {
    edge_kernel_f32<<<2048, 256, 0, stream>>>(erow, ecol, evl, S, ws, ne);
  }
  finalize_kernel<<<16, 256, 0, stream>>>(ws, out, n);
}

// Round 6
// 576.013 us; speedup vs baseline: 1.0027x; 1.0027x over previous
//
#include <hip/hip_runtime.h>
#include <math.h>

#define KC 16
#define DF 256
#define ANB 64            // nodes per assign block

// ws layout
#define WS_POOLED 0          // [16*256] S^T F accumulator (floats)
#define WS_CS     4096       // [16] cluster sizes
#define WS_M      4112       // [16] m_k = sum_e val*S[row][k]
#define WS_TR     4128       // trace accumulator
#define WS_ESUM   4129       // sum of edge_val (= 2*n_edges)
#define WS_TOTAL  4130
#define SHDW_OFF_BYTES 16640 // fp8 S shadow, 16 B/node, 16B-aligned

// NOTE: no __has_builtin / arch preprocessor gating (host/device pass divergence
// caused the round-0 core dump). gfx950 always has the fp8 cvt builtins.

typedef float floatx2 __attribute__((ext_vector_type(2)));

__global__ void zero_ws_kernel(float* __restrict__ ws) {
  int i = blockIdx.x * blockDim.x + threadIdx.x;
  if (i < WS_TOTAL) ws[i] = 0.0f;
}

// 16 fp8 (OCP e4m3fn) -> 16 f32 via 8 packed HW converts.
__device__ __forceinline__ void cvt16_fp8(uint4 u, float* f) {
  floatx2 p;
  p = __builtin_amdgcn_cvt_pk_f32_fp8(u.x, false); f[0] = p[0];  f[1] = p[1];
  p = __builtin_amdgcn_cvt_pk_f32_fp8(u.x, true);  f[2] = p[0];  f[3] = p[1];
  p = __builtin_amdgcn_cvt_pk_f32_fp8(u.y, false); f[4] = p[0];  f[5] = p[1];
  p = __builtin_amdgcn_cvt_pk_f32_fp8(u.y, true);  f[6] = p[0];  f[7] = p[1];
  p = __builtin_amdgcn_cvt_pk_f32_fp8(u.z, false); f[8] = p[0];  f[9] = p[1];
  p = __builtin_amdgcn_cvt_pk_f32_fp8(u.z, true);  f[10] = p[0]; f[11] = p[1];
  p = __builtin_amdgcn_cvt_pk_f32_fp8(u.w, false); f[12] = p[0]; f[13] = p[1];
  p = __builtin_amdgcn_cvt_pk_f32_fp8(u.w, true);  f[14] = p[0]; f[15] = p[1];
}

__device__ __forceinline__ void acc_edge1(uint4 A, uint4 B, float vq,
                                          float* m, float& tr, float& es) {
  float a[16], bb[16];
  cvt16_fp8(A, a); cvt16_fp8(B, bb);
  float d = 0.f;
  #pragma unroll
  for (int k = 0; k < 16; ++k) d += a[k] * bb[k];
  tr += vq * d; es += vq;
  #pragma unroll
  for (int k = 0; k < 16; ++k) m[k] += vq * a[k];
}

// ---------------------------------------------------------------------------
// FUSED assign+pool. r5 post-mortem: the 378 us came from the pooled atomic
// tail — 1563 blocks issuing 4096 atomicAdds each in IDENTICAL order onto the
// same 4096 addresses (lockstep same-address RMW chains ~1500 deep). Fix:
// rotate the 16 (c,e) atomic emissions per block (16-case uniform switch so
// all accp[] indices stay compile-time; runtime indexing would spill to
// scratch). Same trick pool_kernel used in r3/r4 (8.4M rotated atomics
// stayed <=68 us). Everything else identical to r5.
// ---------------------------------------------------------------------------
__global__ void __launch_bounds__(256, 4) assign_fused_kernel(
    const float* __restrict__ F, const float* __restrict__ W,
    const float* __restrict__ b, float* __restrict__ S,
    unsigned* __restrict__ Sh, float* __restrict__ ws, int n) {
  __shared__ float Ft[2][64 * 65];   // chunk staging, transposed: [d_local*65 + node]
  __shared__ float Sl[64 * 20];      // S for the block's 64 nodes, stride 20
  const int t = threadIdx.x;
  const int p  = t >> 6;             // wave id 0..3 (feature split)
  const int pu = __builtin_amdgcn_readfirstlane(p);  // explicitly wave-uniform
  const int nl = t & 63;             // node within block
  const int base = blockIdx.x << 6;
  const bool interior = (base + ANB <= n);

  float4 pref[4];
  auto load_chunk = [&](int c) {
    #pragma unroll
    for (int r = 0; r < 4; ++r) {
      const int li = (r << 8) + t;   // 0..1023
      const int nd = li >> 4;        // node 0..63
      const int f4 = li & 15;        // float4 slot within 64-feature chunk
      if (interior || base + nd < n)
        pref[r] = *(const float4*)&F[(size_t)(base + nd) * DF + (c << 6) + (f4 << 2)];
      else
        pref[r] = make_float4(0.f, 0.f, 0.f, 0.f);
    }
  };
  auto store_chunk = [&](int buf) {
    float* __restrict__ Fb = Ft[buf];
    #pragma unroll
    for (int r = 0; r < 4; ++r) {
      const int li = (r << 8) + t;
      const int nd = li >> 4;
      const int d0 = (li & 15) << 2;
      Fb[(d0 + 0) * 65 + nd] = pref[r].x;
      Fb[(d0 + 1) * 65 + nd] = pref[r].y;
      Fb[(d0 + 2) * 65 + nd] = pref[r].z;
      Fb[(d0 + 3) * 65 + nd] = pref[r].w;
    }
  };

  // ---- phase 1: partial logits (wave p covers 16 features per chunk) ----
  float acc[KC];
  #pragma unroll
  for (int k = 0; k < KC; ++k) acc[k] = 0.f;

  load_chunk(0);
  #pragma unroll
  for (int c = 0; c < 4; ++c) {
    store_chunk(c & 1);
    __syncthreads();
    if (c < 3) load_chunk(c + 1);   // next chunk in flight during compute
    const float* __restrict__ Fb = Ft[c & 1];
    #pragma unroll
    for (int j = 0; j < 16; ++j) {
      const float fv = Fb[((pu << 4) + j) * 65 + nl];
      const float* __restrict__ Wg = &W[(size_t)((c << 6) + (pu << 4) + j) * KC];
      #pragma unroll
      for (int k = 0; k < KC; ++k) acc[k] += fv * Wg[k];
    }
    __syncthreads();
  }

  // ---- phase 2: combine the 4 wave-partials via LDS (reuse Ft[0]) ----
  float* __restrict__ red = &Ft[0][0];       // 4096 floats used of 4160
  #pragma unroll
  for (int k4 = 0; k4 < 4; ++k4)
    *(float4*)&red[(size_t)((p << 6) + nl) * KC + (k4 << 2)] =
        make_float4(acc[k4 * 4 + 0], acc[k4 * 4 + 1],
                    acc[k4 * 4 + 2], acc[k4 * 4 + 3]);
  __syncthreads();

  // ---- phase 3: softmax + S/Sh/Sl writes + cluster sizes (wave 0) ----
  if (t < 64) {
    float l[KC];
    #pragma unroll
    for (int k = 0; k < KC; ++k)
      l[k] = red[t * KC + k] + red[(64 + t) * KC + k]
           + red[(128 + t) * KC + k] + red[(192 + t) * KC + k] + b[k];
    float mx = -1e30f;
    #pragma unroll
    for (int k = 0; k < KC; ++k) mx = fmaxf(mx, l[k]);
    float sum = 0.f;
    #pragma unroll
    for (int k = 0; k < KC; ++k) { l[k] = __expf(l[k] - mx); sum += l[k]; }
    const float inv = 1.0f / sum;
    #pragma unroll
    for (int k = 0; k < KC; ++k) l[k] *= inv;
    const bool valid = base + t < n;
    if (!valid) {
      #pragma unroll
      for (int k = 0; k < KC; ++k) l[k] = 0.f;
    }
    if (valid) {
      const int node = base + t;
      float4* __restrict__ So = (float4*)&S[(size_t)node * KC];
      So[0] = make_float4(l[0],  l[1],  l[2],  l[3]);
      So[1] = make_float4(l[4],  l[5],  l[6],  l[7]);
      So[2] = make_float4(l[8],  l[9],  l[10], l[11]);
      So[3] = make_float4(l[12], l[13], l[14], l[15]);
      if (Sh) {
        unsigned w0, w1, w2, w3;
        w0 = __builtin_amdgcn_cvt_pk_fp8_f32(l[0],  l[1],  0,  false);
        w0 = __builtin_amdgcn_cvt_pk_fp8_f32(l[2],  l[3],  w0, true);
        w1 = __builtin_amdgcn_cvt_pk_fp8_f32(l[4],  l[5],  0,  false);
        w1 = __builtin_amdgcn_cvt_pk_fp8_f32(l[6],  l[7],  w1, true);
        w2 = __builtin_amdgcn_cvt_pk_fp8_f32(l[8],  l[9],  0,  false);
        w2 = __builtin_amdgcn_cvt_pk_fp8_f32(l[10], l[11], w2, true);
        w3 = __builtin_amdgcn_cvt_pk_fp8_f32(l[12], l[13], 0,  false);
        w3 = __builtin_amdgcn_cvt_pk_fp8_f32(l[14], l[15], w3, true);
        *(uint4*)&Sh[(size_t)node * 4] = make_uint4(w0, w1, w2, w3);
      }
    }
    #pragma unroll
    for (int k = 0; k < KC; ++k) Sl[t * 20 + k] = l[k];
    // cluster sizes: butterfly over the full wave (t<64 == wave 0)
    #pragma unroll
    for (int off = 1; off < 64; off <<= 1) {
      #pragma unroll
      for (int k = 0; k < KC; ++k) l[k] += __shfl_xor(l[k], off);
    }
    if (t == 0) {
      #pragma unroll
      for (int k = 0; k < KC; ++k) atomicAdd(&ws[WS_CS + k], l[k]);
    }
  }
  __syncthreads();

  // ---- phase 4: pooled partial S^T F, re-staging chunks (L2-hot) ----
  // thread (p,nl): feature column d = c*64 + nl, clusters k = 4p..4p+3
  float accp[16];
  #pragma unroll
  for (int i = 0; i < 16; ++i) accp[i] = 0.f;

  load_chunk(0);
  #pragma unroll
  for (int c = 0; c < 4; ++c) {
    store_chunk(c & 1);
    __syncthreads();
    if (c < 3) load_chunk(c + 1);
    const float* __restrict__ Fb = Ft[c & 1];
    const int kb = p << 2;
    #pragma unroll 8
    for (int node = 0; node < 64; ++node) {
      const float fv = Fb[nl * 65 + node];
      const float4 sv = *(const float4*)&Sl[node * 20 + kb];  // wave-broadcast
      accp[c * 4 + 0] += fv * sv.x;
      accp[c * 4 + 1] += fv * sv.y;
      accp[c * 4 + 2] += fv * sv.z;
      accp[c * 4 + 3] += fv * sv.w;
    }
    __syncthreads();
  }

  // Rotated atomic emission: 16-case uniform switch keeps accp[] indices
  // compile-time while giving each block a different same-address phase.
  #define PA(c, e) atomicAdd(&ws[WS_POOLED + (size_t)((p << 2) + (e)) * DF \
                                 + ((c) << 6) + nl], accp[(c) * 4 + (e)]);
  #define EMIT(i) PA(((i) & 15) >> 2, (i) & 3)
  #define SEQ(r) EMIT(r+0) EMIT(r+1) EMIT(r+2)  EMIT(r+3)  EMIT(r+4)  EMIT(r+5) \
                 EMIT(r+6) EMIT(r+7) EMIT(r+8)  EMIT(r+9)  EMIT(r+10) EMIT(r+11) \
                 EMIT(r+12) EMIT(r+13) EMIT(r+14) EMIT(r+15)
  switch (blockIdx.x & 15) {
    case 0:  { SEQ(0)  } break;
    case 1:  { SEQ(1)  } break;
    case 2:  { SEQ(2)  } break;
    case 3:  { SEQ(3)  } break;
    case 4:  { SEQ(4)  } break;
    case 5:  { SEQ(5)  } break;
    case 6:  { SEQ(6)  } break;
    case 7:  { SEQ(7)  } break;
    case 8:  { SEQ(8)  } break;
    case 9:  { SEQ(9)  } break;
    case 10: { SEQ(10) } break;
    case 11: { SEQ(11) } break;
    case 12: { SEQ(12) } break;
    case 13: { SEQ(13) } break;
    case 14: { SEQ(14) } break;
    default: { SEQ(15) } break;
  }
  #undef SEQ
  #undef EMIT
  #undef PA
}

// ---------------------------------------------------------------------------
// Edge pass (fp8 S): contiguous 2048-edge chunk per block, all 16 S-gathers
// issued into named registers before compute (r4: dropped below top-5).
// ---------------------------------------------------------------------------
__global__ void __launch_bounds__(256) edge_kernel_fp8(
    const int* __restrict__ erow, const int* __restrict__ ecol,
    const float* __restrict__ evl, const uint4* __restrict__ S8,
    float* __restrict__ ws, int ne) {
  __shared__ float red[KC + 2];
  const int t = threadIdx.x;
  if (t < KC + 2) red[t] = 0.0f;
  __syncthreads();

  float m[KC];
  #pragma unroll
  for (int i = 0; i < KC; ++i) m[i] = 0.f;
  float tr = 0.f, es = 0.f;

  const int cbase = blockIdx.x << 11;     // 2048 edges per block
  const int base = cbase + t;
  int r[8], c[8];
  float v[8];
  if (cbase + 2048 <= ne) {               // interior fast path
    #pragma unroll
    for (int i = 0; i < 8; ++i) {
      const int e = base + (i << 8);
      r[i] = erow[e]; c[i] = ecol[e]; v[i] = evl[e];
    }
  } else {
    #pragma unroll
    for (int i = 0; i < 8; ++i) {
      const int e = base + (i << 8);
      const bool ok = e < ne;
      r[i] = ok ? erow[e] : 0;
      c[i] = ok ? ecol[e] : 0;
      v[i] = ok ? evl[e] : 0.f;
    }
  }

  const uint4 A0 = S8[r[0]], B0 = S8[c[0]], A1 = S8[r[1]], B1 = S8[c[1]],
              A2 = S8[r[2]], B2 = S8[c[2]], A3 = S8[r[3]], B3 = S8[c[3]],
              A4 = S8[r[4]], B4 = S8[c[4]], A5 = S8[r[5]], B5 = S8[c[5]],
              A6 = S8[r[6]], B6 = S8[c[6]], A7 = S8[r[7]], B7 = S8[c[7]];
  acc_edge1(A0, B0, v[0], m, tr, es);
  acc_edge1(A1, B1, v[1], m, tr, es);
  acc_edge1(A2, B2, v[2], m, tr, es);
  acc_edge1(A3, B3, v[3], m, tr, es);
  acc_edge1(A4, B4, v[4], m, tr, es);
  acc_edge1(A5, B5, v[5], m, tr, es);
  acc_edge1(A6, B6, v[6], m, tr, es);
  acc_edge1(A7, B7, v[7], m, tr, es);

  #pragma unroll
  for (int off = 1; off < 64; off <<= 1) {
    tr += __shfl_xor(tr, off);
    es += __shfl_xor(es, off);
    #pragma unroll
    for (int i = 0; i < KC; ++i) m[i] += __shfl_xor(m[i], off);
  }
  if ((t & 63) == 0) {
    atomicAdd(&red[KC], tr);
    atomicAdd(&red[KC + 1], es);
    #pragma unroll
    for (int i = 0; i < KC; ++i) atomicAdd(&red[i], m[i]);
  }
  __syncthreads();
  if (t < KC)            atomicAdd(&ws[WS_M + t], red[t]);
  else if (t == KC)      atomicAdd(&ws[WS_TR], red[KC]);
  else if (t == KC + 1)  atomicAdd(&ws[WS_ESUM], red[KC + 1]);
}

// fp32 fallback (ws too small for the fp8 shadow) — runtime choice.
__global__ void __launch_bounds__(256) edge_kernel_f32(
    const int* __restrict__ erow, const int* __restrict__ ecol,
    const float* __restrict__ evl, const float* __restrict__ S,
    float* __restrict__ ws, int ne) {
  __shared__ float red[KC + 2];
  const int t = threadIdx.x;
  if (t < KC + 2) red[t] = 0.0f;
  __syncthreads();
  float m[KC];
  #pragma unroll
  for (int i = 0; i < KC; ++i) m[i] = 0.f;
  float tr = 0.f, es = 0.f;
  const int stride = gridDim.x * blockDim.x;
  for (int e = blockIdx.x * blockDim.x + t; e < ne; e += stride) {
    const int r = erow[e];
    const int c = ecol[e];
    const float v = evl[e];
    const float4* __restrict__ Sr = (const float4*)(S + (size_t)r * KC);
    const float4* __restrict__ Sc = (const float4*)(S + (size_t)c * KC);
    const float4 a0 = Sr[0], a1 = Sr[1], a2 = Sr[2], a3 = Sr[3];
    const float4 b0 = Sc[0], b1 = Sc[1], b2 = Sc[2], b3 = Sc[3];
    float d = a0.x*b0.x + a0.y*b0.y + a0.z*b0.z + a0.w*b0.w
            + a1.x*b1.x + a1.y*b1.y + a1.z*b1.z + a1.w*b1.w
            + a2.x*b2.x + a2.y*b2.y + a2.z*b2.z + a2.w*b2.w
            + a3.x*b3.x + a3.y*b3.y + a3.z*b3.z + a3.w*b3.w;
    tr += v * d; es += v;
    m[0]+=v*a0.x; m[1]+=v*a0.y; m[2]+=v*a0.z; m[3]+=v*a0.w;
    m[4]+=v*a1.x; m[5]+=v*a1.y; m[6]+=v*a1.z; m[7]+=v*a1.w;
    m[8]+=v*a2.x; m[9]+=v*a2.y; m[10]+=v*a2.z; m[11]+=v*a2.w;
    m[12]+=v*a3.x; m[13]+=v*a3.y; m[14]+=v*a3.z; m[15]+=v*a3.w;
  }
  #pragma unroll
  for (int off = 1; off < 64; off <<= 1) {
    tr += __shfl_xor(tr, off);
    es += __shfl_xor(es, off);
    #pragma unroll
    for (int i = 0; i < KC; ++i) m[i] += __shfl_xor(m[i], off);
  }
  if ((t & 63) == 0) {
    atomicAdd(&red[KC], tr);
    atomicAdd(&red[KC + 1], es);
    #pragma unroll
    for (int i = 0; i < KC; ++i) atomicAdd(&red[i], m[i]);
  }
  __syncthreads();
  if (t < KC)            atomicAdd(&ws[WS_M + t], red[t]);
  else if (t == KC)      atomicAdd(&ws[WS_TR], red[KC]);
  else if (t == KC + 1)  atomicAdd(&ws[WS_ESUM], red[KC + 1]);
}

__global__ void finalize_kernel(const float* __restrict__ ws,
                                float* __restrict__ out, int n) {
  const int idx = blockIdx.x * 256 + threadIdx.x;
  const float alpha = 1.6732632423543772f;
  const float scale = 1.0507009873554805f;
  if (idx < KC * DF) {
    const int k = idx >> 8;
    const float x = ws[WS_POOLED + idx] / ws[WS_CS + k];
    const float r = x > 0.f ? x : alpha * expm1f(x);
    out[idx] = scale * r;
  }
  if (idx == 0) {
    const float esum = ws[WS_ESUM];   // = 2 * n_edges
    const float tr = ws[WS_TR];
    float sm2 = 0.f, sc2 = 0.f;
    for (int i = 0; i < KC; ++i) {
      const float mi = ws[WS_M + i];
      sm2 += mi * mi;
      const float ci = ws[WS_CS + i];
      sc2 += ci * ci;
    }
    const float spectral = -(tr - sm2 / esum) / esum;
    const float collapse = 0.1f * (sqrtf(sc2) / (float)n * 4.0f - 1.0f);
    const size_t off = (size_t)(KC * DF) + (size_t)n * KC;
    out[off] = spectral;
    out[off + 1] = collapse;
  }
}

extern "C" void kernel_launch(void* const* d_in, const int* in_sizes, int n_in,
                              void* d_out, int out_size, void* d_ws, size_t ws_size,
                              hipStream_t stream) {
  const float* F   = (const float*)d_in[0];
  const float* W   = (const float*)d_in[1];
  const float* b   = (const float*)d_in[2];
  const int* erow  = (const int*)d_in[3];
  const int* ecol  = (const int*)d_in[4];
  const float* evl = (const float*)d_in[5];
  const int n  = in_sizes[0] / DF;
  const int ne = in_sizes[3];
  float* out = (float*)d_out;
  float* S   = out + KC * DF;      // assignments live directly in d_out
  float* ws  = (float*)d_ws;

  const size_t shadow_bytes = (size_t)n * 16;   // fp8: 16 B/node
  const bool use_shadow = ws_size >= (size_t)SHDW_OFF_BYTES + shadow_bytes + 64;
  unsigned* Sh = use_shadow ? (unsigned*)((char*)d_ws + SHDW_OFF_BYTES) : nullptr;

  zero_ws_kernel<<<(WS_TOTAL + 255) / 256, 256, 0, stream>>>(ws);
  const int ag = (n + ANB - 1) >> 6;
  assign_fused_kernel<<<ag, 256, 0, stream>>>(F, W, b, S, Sh, ws, n);
  if (use_shadow) {
    const int eg = (ne + 2047) >> 11;           // one 2048-edge chunk per block
    edge_kernel_fp8<<<eg, 256, 0, stream>>>(erow, ecol, evl, (const uint4*)Sh, ws, ne);
  } else {
    edge_kernel_f32<<<2048, 256, 0, stream>>>(erow, ecol, evl, S, ws, ne);
  }
  finalize_kernel<<<16, 256, 0, stream>>>(ws, out, n);
}

// Round 7
// 290.393 us; speedup vs baseline: 1.9890x; 1.9836x over previous
//
#include <hip/hip_runtime.h>
#include <math.h>

#define KC 16
#define DF 256

// ws layout
#define WS_POOLED 0          // [16*256] S^T F accumulator (floats)
#define WS_CS     4096       // [16] cluster sizes
#define WS_M      4112       // [16] m_k = sum_e val*S[row][k]
#define WS_TR     4128       // trace accumulator
#define WS_ESUM   4129       // sum of edge_val (= 2*n_edges)
#define WS_TOTAL  4130
#define SHDW_OFF_BYTES 16640 // fp8 S shadow, 16 B/node, 16B-aligned

// NOTE: no __has_builtin / arch preprocessor gating (host/device pass divergence
// caused the round-0 core dump). gfx950 always has the fp8 cvt builtins.

typedef float floatx2 __attribute__((ext_vector_type(2)));

__global__ void zero_ws_kernel(float* __restrict__ ws) {
  int i = blockIdx.x * blockDim.x + threadIdx.x;
  if (i < WS_TOTAL) ws[i] = 0.0f;
}

// 16 fp8 (OCP e4m3fn) -> 16 f32 via 8 packed HW converts.
__device__ __forceinline__ void cvt16_fp8(uint4 u, float* f) {
  floatx2 p;
  p = __builtin_amdgcn_cvt_pk_f32_fp8(u.x, false); f[0] = p[0];  f[1] = p[1];
  p = __builtin_amdgcn_cvt_pk_f32_fp8(u.x, true);  f[2] = p[0];  f[3] = p[1];
  p = __builtin_amdgcn_cvt_pk_f32_fp8(u.y, false); f[4] = p[0];  f[5] = p[1];
  p = __builtin_amdgcn_cvt_pk_f32_fp8(u.y, true);  f[6] = p[0];  f[7] = p[1];
  p = __builtin_amdgcn_cvt_pk_f32_fp8(u.z, false); f[8] = p[0];  f[9] = p[1];
  p = __builtin_amdgcn_cvt_pk_f32_fp8(u.z, true);  f[10] = p[0]; f[11] = p[1];
  p = __builtin_amdgcn_cvt_pk_f32_fp8(u.w, false); f[12] = p[0]; f[13] = p[1];
  p = __builtin_amdgcn_cvt_pk_f32_fp8(u.w, true);  f[14] = p[0]; f[15] = p[1];
}

__device__ __forceinline__ void acc_edge1(uint4 A, uint4 B, float vq,
                                          float* m, float& tr, float& es) {
  float a[16], bb[16];
  cvt16_fp8(A, a); cvt16_fp8(B, bb);
  float d = 0.f;
  #pragma unroll
  for (int k = 0; k < 16; ++k) d += a[k] * bb[k];
  tr += vq * d; es += vq;
  #pragma unroll
  for (int k = 0; k < 16; ++k) m[k] += vq * a[k];
}

// ---------------------------------------------------------------------------
// assignments = softmax(F @ W + b) + cluster sizes + fp8 shadow of S.
// VERBATIM r4 version (measured 70 us): double-buffered LDS, one barrier per
// K-chunk, __launch_bounds__(256,2) so the 8x float4 prefetch stays in flight.
// ---------------------------------------------------------------------------
__global__ void __launch_bounds__(256, 2) assign_kernel(
    const float* __restrict__ F, const float* __restrict__ W,
    const float* __restrict__ b, float* __restrict__ S,
    unsigned* __restrict__ Sh, float* __restrict__ ws, int n) {
  __shared__ float Ft[2][32 * 257];
  __shared__ float cs_l[KC];
  const int t = threadIdx.x;
  if (t < KC) cs_l[t] = 0.0f;
  const int nb = blockIdx.x << 8;
  const int node = nb + t;
  const bool valid = node < n;
  const bool interior = (nb + 256 <= n);

  const int nl = t >> 3;          // staged node within tile (per 'it' offset)
  const int jc = t & 7;           // float4 slot within 32-feature row

  float4 pref[8];
  auto load_chunk = [&](int s) {
    #pragma unroll
    for (int it = 0; it < 8; ++it) {
      const int nn = nl + (it << 5);
      if (interior || nb + nn < n)
        pref[it] = *(const float4*)&F[(size_t)(nb + nn) * DF + (s << 5) + (jc << 2)];
      else
        pref[it] = make_float4(0.f, 0.f, 0.f, 0.f);
    }
  };

  float acc[KC];
  #pragma unroll
  for (int k = 0; k < KC; ++k) acc[k] = 0.f;

  load_chunk(0);
  for (int s = 0; s < 8; ++s) {
    float* __restrict__ B = Ft[s & 1];
    // Writes to buffer (s&1) are safe without a leading barrier: the last
    // reads of this buffer (compute s-2) precede the barrier of iter s-1.
    #pragma unroll
    for (int it = 0; it < 8; ++it) {
      const int nn = nl + (it << 5);
      const int d0 = jc << 2;
      B[(d0 + 0) * 257 + nn] = pref[it].x;
      B[(d0 + 1) * 257 + nn] = pref[it].y;
      B[(d0 + 2) * 257 + nn] = pref[it].z;
      B[(d0 + 3) * 257 + nn] = pref[it].w;
    }
    __syncthreads();
    if (s < 7) load_chunk(s + 1);  // in flight during compute below
    #pragma unroll
    for (int j = 0; j < 8; ++j) {
      const float fv0 = B[(4 * j + 0) * 257 + t];
      const float fv1 = B[(4 * j + 1) * 257 + t];
      const float fv2 = B[(4 * j + 2) * 257 + t];
      const float fv3 = B[(4 * j + 3) * 257 + t];
      const float* __restrict__ Wg = &W[(size_t)((s << 5) + (j << 2)) * KC];
      #pragma unroll
      for (int k = 0; k < KC; ++k)
        acc[k] += fv0 * Wg[k] + fv1 * Wg[KC + k]
                + fv2 * Wg[2 * KC + k] + fv3 * Wg[3 * KC + k];
    }
  }

  // thread-local softmax
  float mx = -1e30f;
  #pragma unroll
  for (int k = 0; k < KC; ++k) { acc[k] += b[k]; mx = fmaxf(mx, acc[k]); }
  float sum = 0.f;
  #pragma unroll
  for (int k = 0; k < KC; ++k) { acc[k] = __expf(acc[k] - mx); sum += acc[k]; }
  const float inv = 1.0f / sum;
  #pragma unroll
  for (int k = 0; k < KC; ++k) acc[k] *= inv;
  if (!valid) {
    #pragma unroll
    for (int k = 0; k < KC; ++k) acc[k] = 0.f;
  }
  if (valid) {
    float4* __restrict__ So = (float4*)&S[(size_t)node * KC];
    So[0] = make_float4(acc[0],  acc[1],  acc[2],  acc[3]);
    So[1] = make_float4(acc[4],  acc[5],  acc[6],  acc[7]);
    So[2] = make_float4(acc[8],  acc[9],  acc[10], acc[11]);
    So[3] = make_float4(acc[12], acc[13], acc[14], acc[15]);
    if (Sh) {
      unsigned w0, w1, w2, w3;
      w0 = __builtin_amdgcn_cvt_pk_fp8_f32(acc[0],  acc[1],  0,  false);
      w0 = __builtin_amdgcn_cvt_pk_fp8_f32(acc[2],  acc[3],  w0, true);
      w1 = __builtin_amdgcn_cvt_pk_fp8_f32(acc[4],  acc[5],  0,  false);
      w1 = __builtin_amdgcn_cvt_pk_fp8_f32(acc[6],  acc[7],  w1, true);
      w2 = __builtin_amdgcn_cvt_pk_fp8_f32(acc[8],  acc[9],  0,  false);
      w2 = __builtin_amdgcn_cvt_pk_fp8_f32(acc[10], acc[11], w2, true);
      w3 = __builtin_amdgcn_cvt_pk_fp8_f32(acc[12], acc[13], 0,  false);
      w3 = __builtin_amdgcn_cvt_pk_fp8_f32(acc[14], acc[15], w3, true);
      *(uint4*)&Sh[(size_t)node * 4] = make_uint4(w0, w1, w2, w3);
    }
  }
  // cluster sizes
  #pragma unroll
  for (int off = 1; off < 64; off <<= 1) {
    #pragma unroll
    for (int k = 0; k < KC; ++k) acc[k] += __shfl_xor(acc[k], off);
  }
  if ((t & 63) == 0) {
    #pragma unroll
    for (int k = 0; k < KC; ++k) atomicAdd(&cs_l[k], acc[k]);
  }
  __syncthreads();
  if (t < KC) atomicAdd(&ws[WS_CS + t], cs_l[t]);
}

// ---------------------------------------------------------------------------
// Edge body (fp8): verbatim r4/r6 structure — contiguous 2048-edge chunk per
// block 'idx', all 16 S-gathers into named registers before compute.
// ---------------------------------------------------------------------------
__device__ __forceinline__ void edge_body_fp8(
    const int* __restrict__ erow, const int* __restrict__ ecol,
    const float* __restrict__ evl, const uint4* __restrict__ S8,
    float* __restrict__ ws, int ne, int idx, float* __restrict__ red) {
  const int t = threadIdx.x;
  if (t < KC + 2) red[t] = 0.0f;
  __syncthreads();

  float m[KC];
  #pragma unroll
  for (int i = 0; i < KC; ++i) m[i] = 0.f;
  float tr = 0.f, es = 0.f;

  const int cbase = idx << 11;            // 2048 edges per block
  const int base = cbase + t;
  int r[8], c[8];
  float v[8];
  if (cbase + 2048 <= ne) {               // interior fast path
    #pragma unroll
    for (int i = 0; i < 8; ++i) {
      const int e = base + (i << 8);
      r[i] = erow[e]; c[i] = ecol[e]; v[i] = evl[e];
    }
  } else {
    #pragma unroll
    for (int i = 0; i < 8; ++i) {
      const int e = base + (i << 8);
      const bool ok = e < ne;
      r[i] = ok ? erow[e] : 0;
      c[i] = ok ? ecol[e] : 0;
      v[i] = ok ? evl[e] : 0.f;
    }
  }

  const uint4 A0 = S8[r[0]], B0 = S8[c[0]], A1 = S8[r[1]], B1 = S8[c[1]],
              A2 = S8[r[2]], B2 = S8[c[2]], A3 = S8[r[3]], B3 = S8[c[3]],
              A4 = S8[r[4]], B4 = S8[c[4]], A5 = S8[r[5]], B5 = S8[c[5]],
              A6 = S8[r[6]], B6 = S8[c[6]], A7 = S8[r[7]], B7 = S8[c[7]];
  acc_edge1(A0, B0, v[0], m, tr, es);
  acc_edge1(A1, B1, v[1], m, tr, es);
  acc_edge1(A2, B2, v[2], m, tr, es);
  acc_edge1(A3, B3, v[3], m, tr, es);
  acc_edge1(A4, B4, v[4], m, tr, es);
  acc_edge1(A5, B5, v[5], m, tr, es);
  acc_edge1(A6, B6, v[6], m, tr, es);
  acc_edge1(A7, B7, v[7], m, tr, es);

  #pragma unroll
  for (int off = 1; off < 64; off <<= 1) {
    tr += __shfl_xor(tr, off);
    es += __shfl_xor(es, off);
    #pragma unroll
    for (int i = 0; i < KC; ++i) m[i] += __shfl_xor(m[i], off);
  }
  if ((t & 63) == 0) {
    atomicAdd(&red[KC], tr);
    atomicAdd(&red[KC + 1], es);
    #pragma unroll
    for (int i = 0; i < KC; ++i) atomicAdd(&red[i], m[i]);
  }
  __syncthreads();
  if (t < KC)            atomicAdd(&ws[WS_M + t], red[t]);
  else if (t == KC)      atomicAdd(&ws[WS_TR], red[KC]);
  else if (t == KC + 1)  atomicAdd(&ws[WS_ESUM], red[KC + 1]);
}

// ---------------------------------------------------------------------------
// Pool body: verbatim r4 pool_kernel (measured <=68 us) with explicit
// (idx, pg) replacing (blockIdx.x, gridDim.x).
// ---------------------------------------------------------------------------
__device__ __forceinline__ void pool_body(
    const float* __restrict__ F, const float* __restrict__ S,
    float* __restrict__ ws, int n, int idx, int pg) {
  const int t = threadIdx.x;
  float acc[KC];
  #pragma unroll
  for (int i = 0; i < KC; ++i) acc[i] = 0.f;

  const int nch = n >> 5;
  for (int ch = idx; ch < nch; ch += pg) {
    const int base = ch << 5;
    float fl[32];
    #pragma unroll
    for (int i = 0; i < 32; ++i)
      fl[i] = F[(size_t)(base + i) * DF + t];
    #pragma unroll
    for (int i = 0; i < 32; ++i) {
      const float4* __restrict__ Sr = (const float4*)(S + (size_t)(base + i) * KC);
      const float4 s0 = Sr[0], s1 = Sr[1], s2 = Sr[2], s3 = Sr[3];
      const float f = fl[i];
      acc[0]+=f*s0.x;  acc[1]+=f*s0.y;  acc[2]+=f*s0.z;  acc[3]+=f*s0.w;
      acc[4]+=f*s1.x;  acc[5]+=f*s1.y;  acc[6]+=f*s1.z;  acc[7]+=f*s1.w;
      acc[8]+=f*s2.x;  acc[9]+=f*s2.y;  acc[10]+=f*s2.z; acc[11]+=f*s2.w;
      acc[12]+=f*s3.x; acc[13]+=f*s3.y; acc[14]+=f*s3.z; acc[15]+=f*s3.w;
    }
  }
  if (idx == 0) {                        // tail (n % 32)
    for (int i2 = nch << 5; i2 < n; ++i2) {
      const float f = F[(size_t)i2 * DF + t];
      const float* __restrict__ Sr = S + (size_t)i2 * KC;
      #pragma unroll
      for (int kk = 0; kk < KC; ++kk) acc[kk] += f * Sr[kk];
    }
  }
  const int rot = idx & 15;
  #pragma unroll
  for (int kk = 0; kk < KC; ++kk) {
    const int kidx = (kk + rot) & 15;
    atomicAdd(&ws[WS_POOLED + kidx * DF + t], acc[kidx]);
  }
}

// ---------------------------------------------------------------------------
// Merged edge+pool dispatch: even/odd block interleave keeps both workloads
// co-resident on every CU (edge = latency/gather-bound, pool = stream-BW) and
// removes one launch gap + one kernel tail.
// ---------------------------------------------------------------------------
__global__ void __launch_bounds__(256) edge_pool_kernel(
    const int* __restrict__ erow, const int* __restrict__ ecol,
    const float* __restrict__ evl, const uint4* __restrict__ S8,
    const float* __restrict__ F, const float* __restrict__ S,
    float* __restrict__ ws, int ne, int n, int pg, int eg) {
  __shared__ float red[KC + 2];
  const int bid = blockIdx.x;
  const int mn = pg < eg ? pg : eg;
  const int nInter = 2 * mn;
  int role, idx;
  if (bid < nInter) { role = bid & 1; idx = bid >> 1; }
  else {
    const int rem = bid - nInter;
    role = (pg > eg) ? 0 : 1;
    idx = mn + rem;
  }
  if (role == 0) pool_body(F, S, ws, n, idx, pg);
  else           edge_body_fp8(erow, ecol, evl, S8, ws, ne, idx, red);
}

// fp32 fallback (ws too small for the fp8 shadow) — runtime choice.
__global__ void __launch_bounds__(256) edge_kernel_f32(
    const int* __restrict__ erow, const int* __restrict__ ecol,
    const float* __restrict__ evl, const float* __restrict__ S,
    float* __restrict__ ws, int ne) {
  __shared__ float red[KC + 2];
  const int t = threadIdx.x;
  if (t < KC + 2) red[t] = 0.0f;
  __syncthreads();
  float m[KC];
  #pragma unroll
  for (int i = 0; i < KC; ++i) m[i] = 0.f;
  float tr = 0.f, es = 0.f;
  const int stride = gridDim.x * blockDim.x;
  for (int e = blockIdx.x * blockDim.x + t; e < ne; e += stride) {
    const int r = erow[e];
    const int c = ecol[e];
    const float v = evl[e];
    const float4* __restrict__ Sr = (const float4*)(S + (size_t)r * KC);
    const float4* __restrict__ Sc = (const float4*)(S + (size_t)c * KC);
    const float4 a0 = Sr[0], a1 = Sr[1], a2 = Sr[2], a3 = Sr[3];
    const float4 b0 = Sc[0], b1 = Sc[1], b2 = Sc[2], b3 = Sc[3];
    float d = a0.x*b0.x + a0.y*b0.y + a0.z*b0.z + a0.w*b0.w
            + a1.x*b1.x + a1.y*b1.y + a1.z*b1.z + a1.w*b1.w
            + a2.x*b2.x + a2.y*b2.y + a2.z*b2.z + a2.w*b2.w
            + a3.x*b3.x + a3.y*b3.y + a3.z*b3.z + a3.w*b3.w;
    tr += v * d; es += v;
    m[0]+=v*a0.x; m[1]+=v*a0.y; m[2]+=v*a0.z; m[3]+=v*a0.w;
    m[4]+=v*a1.x; m[5]+=v*a1.y; m[6]+=v*a1.z; m[7]+=v*a1.w;
    m[8]+=v*a2.x; m[9]+=v*a2.y; m[10]+=v*a2.z; m[11]+=v*a2.w;
    m[12]+=v*a3.x; m[13]+=v*a3.y; m[14]+=v*a3.z; m[15]+=v*a3.w;
  }
  #pragma unroll
  for (int off = 1; off < 64; off <<= 1) {
    tr += __shfl_xor(tr, off);
    es += __shfl_xor(es, off);
    #pragma unroll
    for (int i = 0; i < KC; ++i) m[i] += __shfl_xor(m[i], off);
  }
  if ((t & 63) == 0) {
    atomicAdd(&red[KC], tr);
    atomicAdd(&red[KC + 1], es);
    #pragma unroll
    for (int i = 0; i < KC; ++i) atomicAdd(&red[i], m[i]);
  }
  __syncthreads();
  if (t < KC)            atomicAdd(&ws[WS_M + t], red[t]);
  else if (t == KC)      atomicAdd(&ws[WS_TR], red[KC]);
  else if (t == KC + 1)  atomicAdd(&ws[WS_ESUM], red[KC + 1]);
}

__global__ void finalize_kernel(const float* __restrict__ ws,
                                float* __restrict__ out, int n) {
  const int idx = blockIdx.x * 256 + threadIdx.x;
  const float alpha = 1.6732632423543772f;
  const float scale = 1.0507009873554805f;
  if (idx < KC * DF) {
    const int k = idx >> 8;
    const float x = ws[WS_POOLED + idx] / ws[WS_CS + k];
    const float r = x > 0.f ? x : alpha * expm1f(x);
    out[idx] = scale * r;
  }
  if (idx == 0) {
    const float esum = ws[WS_ESUM];   // = 2 * n_edges
    const float tr = ws[WS_TR];
    float sm2 = 0.f, sc2 = 0.f;
    for (int i = 0; i < KC; ++i) {
      const float mi = ws[WS_M + i];
      sm2 += mi * mi;
      const float ci = ws[WS_CS + i];
      sc2 += ci * ci;
    }
    const float spectral = -(tr - sm2 / esum) / esum;
    const float collapse = 0.1f * (sqrtf(sc2) / (float)n * 4.0f - 1.0f);
    const size_t off = (size_t)(KC * DF) + (size_t)n * KC;
    out[off] = spectral;
    out[off + 1] = collapse;
  }
}

extern "C" void kernel_launch(void* const* d_in, const int* in_sizes, int n_in,
                              void* d_out, int out_size, void* d_ws, size_t ws_size,
                              hipStream_t stream) {
  const float* F   = (const float*)d_in[0];
  const float* W   = (const float*)d_in[1];
  const float* b   = (const float*)d_in[2];
  const int* erow  = (const int*)d_in[3];
  const int* ecol  = (const int*)d_in[4];
  const float* evl = (const float*)d_in[5];
  const int n  = in_sizes[0] / DF;
  const int ne = in_sizes[3];
  float* out = (float*)d_out;
  float* S   = out + KC * DF;      // assignments live directly in d_out
  float* ws  = (float*)d_ws;

  const size_t shadow_bytes = (size_t)n * 16;   // fp8: 16 B/node
  const bool use_shadow = ws_size >= (size_t)SHDW_OFF_BYTES + shadow_bytes + 64;
  unsigned* Sh = use_shadow ? (unsigned*)((char*)d_ws + SHDW_OFF_BYTES) : nullptr;

  zero_ws_kernel<<<(WS_TOTAL + 255) / 256, 256, 0, stream>>>(ws);
  assign_kernel<<<(n + 255) / 256, 256, 0, stream>>>(F, W, b, S, Sh, ws, n);

  const int pg = 2048;                          // pool blocks
  if (use_shadow) {
    const int eg = (ne + 2047) >> 11;           // edge blocks (2048 edges each)
    edge_pool_kernel<<<pg + eg, 256, 0, stream>>>(
        erow, ecol, evl, (const uint4*)Sh, F, S, ws, ne, n, pg, eg);
  } else {
    edge_kernel_f32<<<2048, 256, 0, stream>>>(erow, ecol, evl, S, ws, ne);
    edge_pool_kernel<<<pg, 256, 0, stream>>>(    // pure pool (eg = 0)
        erow, ecol, evl, (const uint4*)nullptr, F, S, ws, ne, n, pg, 0);
  }
  finalize_kernel<<<16, 256, 0, stream>>>(ws, out, n);
}